// Round 5
// baseline (309.270 us; speedup 1.0000x reference)
//
#include <hip/hip_runtime.h>
#include <hip/hip_bf16.h>
#include <cstdint>

#define BF16 __hip_bfloat16

typedef __attribute__((ext_vector_type(8))) short bhalf8;   // 8 bf16 (4 VGPRs)
typedef __attribute__((ext_vector_type(4))) float floatx4;  // 4 fp32 acc

#define MFMA16(a, b, c) __builtin_amdgcn_mfma_f32_16x16x32_bf16((a), (b), (c), 0, 0, 0)

#define MASKV (-30000.0f)
#define QSCALE 0.18033688011112042f  // 0.125 * log2(e); folded into Q

__device__ __forceinline__ void async_cp16(const void* gsrc, void* ldst) {
  // lane i writes lds_base + i*16; base must be wave-uniform (m104/m108)
  __builtin_amdgcn_global_load_lds(
      (__attribute__((address_space(1))) void*)(size_t)gsrc,
      (__attribute__((address_space(3))) void*)ldst, 16, 0, 0);
}

__device__ __forceinline__ bhalf8 cvt8(const float* p) {
  const float4 f0 = *(const float4*)p;
  const float4 f1 = *(const float4*)(p + 4);
  union { bhalf8 v; ushort u[8]; } r;
  const float t[8] = {f0.x, f0.y, f0.z, f0.w, f1.x, f1.y, f1.z, f1.w};
#pragma unroll
  for (int i = 0; i < 8; ++i) {
    BF16 h = __float2bfloat16(t[i]);
    r.u[i] = *(const ushort*)&h;
  }
  return r.v;
}

// ---------------------------------------------------------------------------
// Bulk f32 -> bf16 convert, 8 elems/thread.
// ---------------------------------------------------------------------------
__global__ void cvt_f32_bf16(const float* __restrict__ in, BF16* __restrict__ out) {
  const size_t i = ((size_t)blockIdx.x * 256 + threadIdx.x) * 8;
  *(bhalf8*)(out + i) = cvt8(in + i);
}

// ---------------------------------------------------------------------------
// Transpose+convert (R x C) f32 -> (C x R) bf16. Block (32,8), LDS 32x33 pad.
// ---------------------------------------------------------------------------
__global__ void transpose_cvt(const float* __restrict__ in, ushort* __restrict__ out,
                              int R, int C) {
  __shared__ ushort t[32][33];
  const int c0 = blockIdx.x * 32, r0 = blockIdx.y * 32;
  const int tx = threadIdx.x, ty = threadIdx.y;
#pragma unroll
  for (int j = 0; j < 32; j += 8) {
    BF16 h = __float2bfloat16(in[(size_t)(r0 + ty + j) * C + c0 + tx]);
    t[ty + j][tx] = *(const ushort*)&h;
  }
  __syncthreads();
#pragma unroll
  for (int j = 0; j < 32; j += 8)
    out[(size_t)(c0 + ty + j) * R + r0 + tx] = t[tx][ty + j];
}

// ---------------------------------------------------------------------------
// GEMM C = A(MxK,bf16) * Bt(NxK,bf16)^T + bias(f32), fp32 accum.
// 128x128 tile, BK=64, 4 waves (2x2 of 64x64), 16x16x32 MFMA.
// m97 staging: global_load_lds width=16, 2-barrier K-loop.
// LDS: 1024 slots of 16B; slot = row*8 + g holds k-group (g - row) & 7.
// MODE 0: float out, C0f[m*Nd + n] = v + bias[n]
// MODE 1: bf16 QKV scatter: n->(which,h,d); Q (x QSCALE)/K as (B,H,S,64),
//         V^T as (B,H,64,S)
// ---------------------------------------------------------------------------
template <int MODE>
__global__ __launch_bounds__(256, 2) void gemm_bt(
    const BF16* __restrict__ A, const BF16* __restrict__ Bt, const float* __restrict__ bias,
    void* __restrict__ C0v, BF16* __restrict__ C1, BF16* __restrict__ C2,
    int Md, int Nd, int Kd) {
  __shared__ __align__(16) BF16 As[128 * 64];
  __shared__ __align__(16) BF16 Bs[128 * 64];

  const int tid = threadIdx.x;
  const int w = tid >> 6, lane = tid & 63;
  const int lm = lane & 15, quad = lane >> 4;
  const int wm = (w >> 1) * 64, wn = (w & 1) * 64;
  const int tile_m = blockIdx.y * 128, tile_n = blockIdx.x * 128;

  floatx4 acc[4][4];
#pragma unroll
  for (int i = 0; i < 4; ++i)
#pragma unroll
    for (int j = 0; j < 4; ++j) acc[i][j] = (floatx4){0.f, 0.f, 0.f, 0.f};

  for (int k0 = 0; k0 < Kd; k0 += 64) {
    __syncthreads();  // previous iter's LDS reads complete
#pragma unroll
    for (int j = 0; j < 4; ++j) {
      const int sb = (j * 4 + w) * 64;  // wave-uniform slot base
      const int slot = sb + lane;
      const int row = slot >> 3;
      const int gs = ((slot & 7) - row) & 7;
      async_cp16(A + (size_t)(tile_m + row) * Kd + k0 + gs * 8, As + sb * 8);
      async_cp16(Bt + (size_t)(tile_n + row) * Kd + k0 + gs * 8, Bs + sb * 8);
    }
    __syncthreads();  // drains vmcnt (m97 structure)

#pragma unroll
    for (int s = 0; s < 2; ++s) {
      bhalf8 af[4], bfr[4];
#pragma unroll
      for (int mt = 0; mt < 4; ++mt) {
        const int r = wm + mt * 16 + lm;
        const int g = ((s * 4 + quad) + r) & 7;
        af[mt] = *(const bhalf8*)(As + r * 64 + g * 8);
      }
#pragma unroll
      for (int nt = 0; nt < 4; ++nt) {
        const int r = wn + nt * 16 + lm;
        const int g = ((s * 4 + quad) + r) & 7;
        bfr[nt] = *(const bhalf8*)(Bs + r * 64 + g * 8);
      }
#pragma unroll
      for (int mt = 0; mt < 4; ++mt)
#pragma unroll
        for (int nt = 0; nt < 4; ++nt)
          acc[mt][nt] = MFMA16(af[mt], bfr[nt], acc[mt][nt]);
    }
  }

  // Epilogue. C layout: col = lane&15, row = quad*4 + reg (m89/m91).
#pragma unroll
  for (int nt = 0; nt < 4; ++nt) {
    const int n = tile_n + wn + nt * 16 + lm;
    const float bv = bias[n];
#pragma unroll
    for (int mt = 0; mt < 4; ++mt) {
      const int m0 = tile_m + wm + mt * 16 + quad * 4;
      floatx4 v = acc[mt][nt];
      if (MODE == 0) {
        float* C0f = (float*)C0v;
#pragma unroll
        for (int r = 0; r < 4; ++r)
          C0f[(size_t)(m0 + r) * Nd + n] = v[r] + bv;
      } else {
        const int which = n >> 10;
        const int h = (n >> 6) & 15;
        const int d = n & 63;
        if (which == 2) {
          // V^T: 4 regs = 4 consecutive s at fixed d -> one 8 B store
          const int b = m0 >> 11, s0 = m0 & 2047;
          union { ushort4 u4; ushort u[4]; } pk;
#pragma unroll
          for (int r = 0; r < 4; ++r) {
            BF16 hv = __float2bfloat16(v[r] + bv);
            pk.u[r] = *(const ushort*)&hv;
          }
          *(ushort4*)(C2 + ((size_t)((b * 16 + h) * 64 + d)) * 2048 + s0) = pk.u4;
        } else {
          BF16* dst = (which == 0) ? (BF16*)C0v : C1;
          const float sc = (which == 0) ? QSCALE : 1.0f;  // fold softmax scale into Q
#pragma unroll
          for (int r = 0; r < 4; ++r) {
            const int m = m0 + r, b = m >> 11, si = m & 2047;
            dst[((size_t)(b * 16 + h) * 2048 + si) * 64 + d] =
                __float2bfloat16((v[r] + bv) * sc);
          }
        }
      }
    }
  }
}

// ---------------------------------------------------------------------------
// Causal flash attention, transposed-score formulation, BQ=128.
// Q (pre-scaled), K: (B*H,S,64); VT: (B*H,64,S); O: (B*S,1024) bf16.
// 4 waves; wave w owns q-rows [qt*128 + w*32, +32) as two 16-row sets.
// Per 64-wide k-tile: S^T = K·Q^T (col = q-row = lane&15 -> in-lane softmax,
// 2 shuffles), O^T += V^T·P^T. Fully-masked set-tiles skipped (wave-uniform).
// ---------------------------------------------------------------------------
__global__ __launch_bounds__(256, 2) void flash_attn(
    const BF16* __restrict__ Q, const BF16* __restrict__ Kmat,
    const BF16* __restrict__ VT, BF16* __restrict__ O) {
  __shared__ __align__(16) BF16 Ks[64 * 64];
  __shared__ __align__(16) BF16 Vs[64 * 64];
  __shared__ __align__(16) BF16 Ps[4 * 32 * 64];  // per wave: 2 sets x 16 x 64

  const int bh = blockIdx.y;
  const int qt = (int)gridDim.x - 1 - (int)blockIdx.x;  // big tiles first
  const int tid = threadIdx.x;
  const int w = tid >> 6, lane = tid & 63;
  const int lm = lane & 15, quad = lane >> 4;
  const size_t bh_off = (size_t)bh * (2048 * 64);

  const int qb0 = qt * 128 + w * 32;  // set s2 covers rows qb0 + s2*16 .. +15

  // Q B-fragments: B[n=q-row=lane&15][d=quad*8+j] (+32 for 2nd MFMA)
  bhalf8 aq[2][2];
#pragma unroll
  for (int s2 = 0; s2 < 2; ++s2) {
    const size_t qoff = bh_off + (size_t)(qb0 + s2 * 16 + lm) * 64;
    aq[s2][0] = *(const bhalf8*)(Q + qoff + quad * 8);
    aq[s2][1] = *(const bhalf8*)(Q + qoff + 32 + quad * 8);
  }

  floatx4 oacc[2][4];  // O^T per set: C[row=d_local][col=q=lm]
  float m_i[2], l_i[2];
#pragma unroll
  for (int s2 = 0; s2 < 2; ++s2) {
    m_i[s2] = MASKV;
    l_i[s2] = 0.f;
#pragma unroll
    for (int i = 0; i < 4; ++i) oacc[s2][i] = (floatx4){0.f, 0.f, 0.f, 0.f};
  }

  int srow[2], sgs[2], sslot[2];
#pragma unroll
  for (int j = 0; j < 2; ++j) {
    const int slot = (w * 2 + j) * 64 + lane;
    sslot[j] = slot;
    srow[j] = slot >> 3;
    sgs[j] = ((slot & 7) - (slot >> 3)) & 7;
  }
  BF16* pw = Ps + w * (32 * 64);

  bhalf8 kv[2], vv[2], nkv[2], nvv[2];
  {
    const BF16* Kg = Kmat + bh_off;
    const BF16* Vg = VT + bh_off;
#pragma unroll
    for (int j = 0; j < 2; ++j) {
      kv[j] = *(const bhalf8*)(Kg + srow[j] * 64 + sgs[j] * 8);
      vv[j] = *(const bhalf8*)(Vg + (size_t)srow[j] * 2048 + sgs[j] * 8);
    }
  }

  const int ktmax = 2 * qt + 1;
  for (int kt = 0; kt <= ktmax; ++kt) {
    __syncthreads();  // prior iter's Ks/Vs reads complete
#pragma unroll
    for (int j = 0; j < 2; ++j) {
      *(bhalf8*)(Ks + sslot[j] * 8) = kv[j];
      *(bhalf8*)(Vs + sslot[j] * 8) = vv[j];
    }
    __syncthreads();

    if (kt < ktmax) {  // prefetch next tile; latency overlaps compute below
      const BF16* Kg = Kmat + bh_off + (size_t)((kt + 1) * 64) * 64;
      const BF16* Vg = VT + bh_off + (kt + 1) * 64;
#pragma unroll
      for (int j = 0; j < 2; ++j) {
        nkv[j] = *(const bhalf8*)(Kg + srow[j] * 64 + sgs[j] * 8);
        nvv[j] = *(const bhalf8*)(Vg + (size_t)srow[j] * 2048 + sgs[j] * 8);
      }
    }

    const int k0 = kt * 64;
#pragma unroll
    for (int s2 = 0; s2 < 2; ++s2) {
      const int qb = qb0 + s2 * 16;
      if (k0 > qb + 15) continue;  // fully masked (wave-uniform branch)

      // S^T = K·Q^T : C[row=kcol][col=qrow]
      floatx4 st[4];
#pragma unroll
      for (int nt = 0; nt < 4; ++nt) {
        const int rr = nt * 16 + lm;
        const bhalf8 ak0 = *(const bhalf8*)(Ks + rr * 64 + ((quad + rr) & 7) * 8);
        const bhalf8 ak1 = *(const bhalf8*)(Ks + rr * 64 + ((4 + quad + rr) & 7) * 8);
        floatx4 z = (floatx4){0.f, 0.f, 0.f, 0.f};
        z = MFMA16(ak0, aq[s2][0], z);
        z = MFMA16(ak1, aq[s2][1], z);
        st[nt] = z;
      }

      if (k0 + 63 > qb) {  // boundary tile: per-element causal mask
#pragma unroll
        for (int nt = 0; nt < 4; ++nt)
#pragma unroll
          for (int r = 0; r < 4; ++r)
            if ((k0 + nt * 16 + quad * 4 + r) > (qb + lm)) st[nt][r] = MASKV;
      }

      // online softmax (log2 domain): in-lane over 16 regs + 2 shuffles
      float mx = MASKV;
#pragma unroll
      for (int nt = 0; nt < 4; ++nt)
#pragma unroll
        for (int r = 0; r < 4; ++r) mx = fmaxf(mx, st[nt][r]);
      mx = fmaxf(mx, __shfl_xor(mx, 16, 64));
      mx = fmaxf(mx, __shfl_xor(mx, 32, 64));
      const float mnew = fmaxf(m_i[s2], mx);
      const float alpha = __builtin_amdgcn_exp2f(m_i[s2] - mnew);
      m_i[s2] = mnew;

      float rs = 0.f;
#pragma unroll
      for (int nt = 0; nt < 4; ++nt)
#pragma unroll
        for (int r = 0; r < 4; ++r) {
          const float p = __builtin_amdgcn_exp2f(st[nt][r] - mnew);
          st[nt][r] = p;
          rs += p;
        }
      rs += __shfl_xor(rs, 16, 64);
      rs += __shfl_xor(rs, 32, 64);
      l_i[s2] = l_i[s2] * alpha + rs;
#pragma unroll
      for (int dn = 0; dn < 4; ++dn) oacc[s2][dn] *= alpha;

      // P^T -> per-wave LDS: row = q (lm), 4 consecutive k -> 8 B write
      BF16* pws = pw + s2 * (16 * 64);
#pragma unroll
      for (int nt = 0; nt < 4; ++nt) {
        union { ushort4 u4; ushort u[4]; } pk;
#pragma unroll
        for (int r = 0; r < 4; ++r) {
          BF16 h = __float2bfloat16(st[nt][r]);
          pk.u[r] = *(const ushort*)&h;
        }
        const int g = ((nt * 2 + (quad >> 1)) + lm) & 7;
        *(ushort4*)(pws + lm * 64 + g * 8 + (quad & 1) * 4) = pk.u4;
      }

      // O^T += V^T·P^T
      const bhalf8 ap0 = *(const bhalf8*)(pws + lm * 64 + ((quad + lm) & 7) * 8);
      const bhalf8 ap1 = *(const bhalf8*)(pws + lm * 64 + ((4 + quad + lm) & 7) * 8);
#pragma unroll
      for (int dn = 0; dn < 4; ++dn) {
        const int rr = dn * 16 + lm;
        const bhalf8 av0 = *(const bhalf8*)(Vs + rr * 64 + ((quad + rr) & 7) * 8);
        const bhalf8 av1 = *(const bhalf8*)(Vs + rr * 64 + ((4 + quad + rr) & 7) * 8);
        oacc[s2][dn] = MFMA16(av0, ap0, oacc[s2][dn]);
        oacc[s2][dn] = MFMA16(av1, ap1, oacc[s2][dn]);
      }
    }

#pragma unroll
    for (int j = 0; j < 2; ++j) { kv[j] = nkv[j]; vv[j] = nvv[j]; }
  }

  // normalize + store merged-heads (B*S, 1024); 4 consecutive d -> 8 B store
  const int b = bh >> 4, h = bh & 15;
#pragma unroll
  for (int s2 = 0; s2 < 2; ++s2) {
    const float inv_l = 1.0f / l_i[s2];
    const size_t orow = (size_t)(b * 2048 + qb0 + s2 * 16 + lm) * 1024 + h * 64;
#pragma unroll
    for (int dn = 0; dn < 4; ++dn) {
      union { ushort4 u4; ushort u[4]; } pk;
#pragma unroll
      for (int r = 0; r < 4; ++r) {
        BF16 h2 = __float2bfloat16(oacc[s2][dn][r] * inv_l);
        pk.u[r] = *(const ushort*)&h2;
      }
      *(ushort4*)(O + orow + dn * 16 + quad * 4) = pk.u4;
    }
  }
}

// ---------------------------------------------------------------------------
extern "C" void kernel_launch(void* const* d_in, const int* in_sizes, int n_in,
                              void* d_out, int out_size, void* d_ws, size_t ws_size,
                              hipStream_t stream) {
  const float* x = (const float*)d_in[0];      // (8192, 1024) f32
  const float* w_qkv = (const float*)d_in[1];  // (1024, 3072) f32
  const float* b_qkv = (const float*)d_in[2];  // (3072) f32
  const float* w_fc = (const float*)d_in[3];   // (1024, 1024) f32
  const float* b_fc = (const float*)d_in[4];   // (1024) f32
  float* out = (float*)d_out;                  // (8192, 1024) f32

  BF16* ws = (BF16*)d_ws;
  BF16* wTqkv = ws;                    // 3072*1024 bf16
  BF16* wTfc = wTqkv + 3072 * 1024;    // 1024*1024
  BF16* xb = wTfc + 1024 * 1024;       // 8192*1024 bf16
  BF16* Qb = xb + 8388608;             // (B,H,S,64)  pre-scaled by QSCALE
  BF16* Kb = Qb + 8388608;             // (B,H,S,64)
  BF16* VTb = Kb + 8388608;            // (B,H,64,S)
  BF16* Ob = VTb + 8388608;            // (B*S, 1024)
  // total ~92 MB of d_ws

  cvt_f32_bf16<<<4096, 256, 0, stream>>>(x, xb);
  transpose_cvt<<<dim3(96, 32), dim3(32, 8), 0, stream>>>(w_qkv, (ushort*)wTqkv, 1024, 3072);
  transpose_cvt<<<dim3(32, 32), dim3(32, 8), 0, stream>>>(w_fc, (ushort*)wTfc, 1024, 1024);

  gemm_bt<1><<<dim3(24, 64), 256, 0, stream>>>(
      xb, wTqkv, b_qkv, (void*)Qb, Kb, VTb, 8192, 3072, 1024);
  flash_attn<<<dim3(16, 64), 256, 0, stream>>>(Qb, Kb, VTb, Ob);
  gemm_bt<0><<<dim3(8, 64), 256, 0, stream>>>(
      Ob, wTfc, b_fc, (void*)out, nullptr, nullptr, 8192, 1024, 1024);
}

// Round 6
// 277.344 us; speedup vs baseline: 1.1151x; 1.1151x over previous
//
#include <hip/hip_runtime.h>
#include <hip/hip_bf16.h>
#include <cstdint>

#define BF16 __hip_bfloat16

typedef __attribute__((ext_vector_type(8))) short bhalf8;   // 8 bf16 (4 VGPRs)
typedef __attribute__((ext_vector_type(4))) float floatx4;  // 4 fp32 acc

#define MFMA16(a, b, c) __builtin_amdgcn_mfma_f32_16x16x32_bf16((a), (b), (c), 0, 0, 0)

#define MASKV (-30000.0f)
#define QSCALE 0.18033688011112042f  // 0.125 * log2(e); folded into Q

__device__ __forceinline__ bhalf8 cvt8(const float* p) {
  const float4 f0 = *(const float4*)p;
  const float4 f1 = *(const float4*)(p + 4);
  union { bhalf8 v; ushort u[8]; } r;
  const float t[8] = {f0.x, f0.y, f0.z, f0.w, f1.x, f1.y, f1.z, f1.w};
#pragma unroll
  for (int i = 0; i < 8; ++i) {
    BF16 h = __float2bfloat16(t[i]);
    r.u[i] = *(const ushort*)&h;
  }
  return r.v;
}

// ---------------------------------------------------------------------------
// Bulk f32 -> bf16 convert, 8 elems/thread.
// ---------------------------------------------------------------------------
__global__ void cvt_f32_bf16(const float* __restrict__ in, BF16* __restrict__ out) {
  const size_t i = ((size_t)blockIdx.x * 256 + threadIdx.x) * 8;
  *(bhalf8*)(out + i) = cvt8(in + i);
}

// ---------------------------------------------------------------------------
// Transpose+convert (R x C) f32 -> (C x R) bf16. Block (32,8), LDS 32x33 pad.
// ---------------------------------------------------------------------------
__global__ void transpose_cvt(const float* __restrict__ in, ushort* __restrict__ out,
                              int R, int C) {
  __shared__ ushort t[32][33];
  const int c0 = blockIdx.x * 32, r0 = blockIdx.y * 32;
  const int tx = threadIdx.x, ty = threadIdx.y;
#pragma unroll
  for (int j = 0; j < 32; j += 8) {
    BF16 h = __float2bfloat16(in[(size_t)(r0 + ty + j) * C + c0 + tx]);
    t[ty + j][tx] = *(const ushort*)&h;
  }
  __syncthreads();
#pragma unroll
  for (int j = 0; j < 32; j += 8)
    out[(size_t)(c0 + ty + j) * R + r0 + tx] = t[tx][ty + j];
}

// ---------------------------------------------------------------------------
// GEMM C = A(MxK,bf16) * Bt(NxK,bf16)^T + bias(f32), fp32 accum.
// 128x128 tile, BK=64, 4 waves (2x2 of 64x64), 16x16x32 MFMA.
// Register-prefetch staging (round-4 proven; beats global_load_lds here —
// the prefetch latency overlaps compute across the barrier).
// LDS: 1024 slots of 16B; slot = row*8 + g holds k-group (g - row) & 7.
// MODE 0: float out, C0f[m*Nd + n] = v + bias[n]
// MODE 1: bf16 QKV scatter: n->(which,h,d); Q (x QSCALE)/K as (B,H,S,64),
//         V^T as (B,H,64,S)
// ---------------------------------------------------------------------------
template <int MODE>
__global__ __launch_bounds__(256, 2) void gemm_bt(
    const BF16* __restrict__ A, const BF16* __restrict__ Bt, const float* __restrict__ bias,
    void* __restrict__ C0v, BF16* __restrict__ C1, BF16* __restrict__ C2,
    int Md, int Nd, int Kd) {
  __shared__ __align__(16) BF16 As[128 * 64];
  __shared__ __align__(16) BF16 Bs[128 * 64];

  const int tid = threadIdx.x;
  const int w = tid >> 6, lane = tid & 63;
  const int lm = lane & 15, quad = lane >> 4;
  const int wm = (w >> 1) * 64, wn = (w & 1) * 64;
  const int tile_m = blockIdx.y * 128, tile_n = blockIdx.x * 128;

  floatx4 acc[4][4];
#pragma unroll
  for (int i = 0; i < 4; ++i)
#pragma unroll
    for (int j = 0; j < 4; ++j) acc[i][j] = (floatx4){0.f, 0.f, 0.f, 0.f};

  int srow[4], sgs[4], sslot[4];
#pragma unroll
  for (int j = 0; j < 4; ++j) {
    const int slot = (j * 4 + w) * 64 + lane;
    sslot[j] = slot;
    srow[j] = slot >> 3;
    sgs[j] = ((slot & 7) - (slot >> 3)) & 7;
  }

  bhalf8 va[4], vb[4], nva[4], nvb[4];
#pragma unroll
  for (int j = 0; j < 4; ++j) {
    va[j] = *(const bhalf8*)(A + (size_t)(tile_m + srow[j]) * Kd + sgs[j] * 8);
    vb[j] = *(const bhalf8*)(Bt + (size_t)(tile_n + srow[j]) * Kd + sgs[j] * 8);
  }

  for (int k0 = 0; k0 < Kd; k0 += 64) {
    __syncthreads();  // previous iter's LDS reads complete
#pragma unroll
    for (int j = 0; j < 4; ++j) {
      *(bhalf8*)(As + sslot[j] * 8) = va[j];
      *(bhalf8*)(Bs + sslot[j] * 8) = vb[j];
    }
    __syncthreads();

    if (k0 + 64 < Kd) {  // prefetch next K-tile; latency overlaps compute below
      const int k1 = k0 + 64;
#pragma unroll
      for (int j = 0; j < 4; ++j) {
        nva[j] = *(const bhalf8*)(A + (size_t)(tile_m + srow[j]) * Kd + k1 + sgs[j] * 8);
        nvb[j] = *(const bhalf8*)(Bt + (size_t)(tile_n + srow[j]) * Kd + k1 + sgs[j] * 8);
      }
    }

#pragma unroll
    for (int s = 0; s < 2; ++s) {
      bhalf8 af[4], bfr[4];
#pragma unroll
      for (int mt = 0; mt < 4; ++mt) {
        const int r = wm + mt * 16 + lm;
        const int g = ((s * 4 + quad) + r) & 7;
        af[mt] = *(const bhalf8*)(As + r * 64 + g * 8);
      }
#pragma unroll
      for (int nt = 0; nt < 4; ++nt) {
        const int r = wn + nt * 16 + lm;
        const int g = ((s * 4 + quad) + r) & 7;
        bfr[nt] = *(const bhalf8*)(Bs + r * 64 + g * 8);
      }
#pragma unroll
      for (int mt = 0; mt < 4; ++mt)
#pragma unroll
        for (int nt = 0; nt < 4; ++nt)
          acc[mt][nt] = MFMA16(af[mt], bfr[nt], acc[mt][nt]);
    }
#pragma unroll
    for (int j = 0; j < 4; ++j) { va[j] = nva[j]; vb[j] = nvb[j]; }
  }

  // Epilogue. C layout: col = lane&15, row = quad*4 + reg (m89/m91).
#pragma unroll
  for (int nt = 0; nt < 4; ++nt) {
    const int n = tile_n + wn + nt * 16 + lm;
    const float bv = bias[n];
#pragma unroll
    for (int mt = 0; mt < 4; ++mt) {
      const int m0 = tile_m + wm + mt * 16 + quad * 4;
      floatx4 v = acc[mt][nt];
      if (MODE == 0) {
        float* C0f = (float*)C0v;
#pragma unroll
        for (int r = 0; r < 4; ++r)
          C0f[(size_t)(m0 + r) * Nd + n] = v[r] + bv;
      } else {
        const int which = n >> 10;
        const int h = (n >> 6) & 15;
        const int d = n & 63;
        if (which == 2) {
          // V^T: 4 regs = 4 consecutive s at fixed d -> one 8 B store
          const int b = m0 >> 11, s0 = m0 & 2047;
          union { ushort4 u4; ushort u[4]; } pk;
#pragma unroll
          for (int r = 0; r < 4; ++r) {
            BF16 hv = __float2bfloat16(v[r] + bv);
            pk.u[r] = *(const ushort*)&hv;
          }
          *(ushort4*)(C2 + ((size_t)((b * 16 + h) * 64 + d)) * 2048 + s0) = pk.u4;
        } else {
          BF16* dst = (which == 0) ? (BF16*)C0v : C1;
          const float sc = (which == 0) ? QSCALE : 1.0f;  // fold softmax scale into Q
#pragma unroll
          for (int r = 0; r < 4; ++r) {
            const int m = m0 + r, b = m >> 11, si = m & 2047;
            dst[((size_t)(b * 16 + h) * 2048 + si) * 64 + d] =
                __float2bfloat16((v[r] + bv) * sc);
          }
        }
      }
    }
  }
}

// ---------------------------------------------------------------------------
// Causal flash attention — barrier-free, wave-independent.
// Q (pre-scaled), K: (B*H,S,64); VT: (B*H,64,S); O: (B*S,1024) bf16.
// Each wave owns 64 q-rows (4 sets of 16) of q-tile qt; K/V MFMA A-fragments
// load straight global->VGPR (16 B/lane, no LDS, no __syncthreads). The 4
// sets are independent chains (ILP hides softmax/LDS latency). P^T round-
// trips through a per-wave, per-set LDS region (lgkm only).
// Block x waves take qt = {x, 15-x, 16+x, 31-x}: all blocks do 66 k-tiles.
// ---------------------------------------------------------------------------
__global__ __launch_bounds__(256, 2) void flash_attn(
    const BF16* __restrict__ Q, const BF16* __restrict__ Kmat,
    const BF16* __restrict__ VT, BF16* __restrict__ O) {
  __shared__ __align__(16) BF16 Ps[4][4][16 * 64];  // [wave][set] = 32 KB

  const int tid = threadIdx.x;
  const int w = tid >> 6, lane = tid & 63;
  const int lm = lane & 15, quad = lane >> 4;
  const int bh = blockIdx.y;
  const int x = blockIdx.x;
  const int qt = (w == 0) ? x : (w == 1) ? (15 - x) : (w == 2) ? (16 + x) : (31 - x);
  const int qb0 = qt * 64;
  const size_t bh_off = (size_t)bh * (2048 * 64);

  // Q B-fragments: B[n=q-row=lm][d=quad*8+j] (+32 for 2nd MFMA)
  bhalf8 aq[4][2];
#pragma unroll
  for (int s2 = 0; s2 < 4; ++s2) {
    const BF16* qp = Q + bh_off + (size_t)(qb0 + s2 * 16 + lm) * 64 + quad * 8;
    aq[s2][0] = *(const bhalf8*)qp;
    aq[s2][1] = *(const bhalf8*)(qp + 32);
  }

  floatx4 oacc[4][4];  // [set][dn]: O^T C-layout, col=q=lm, row=d
  float m_i[4], l_i[4];
#pragma unroll
  for (int s2 = 0; s2 < 4; ++s2) {
    m_i[s2] = MASKV;
    l_i[s2] = 0.f;
#pragma unroll
    for (int i = 0; i < 4; ++i) oacc[s2][i] = (floatx4){0.f, 0.f, 0.f, 0.f};
  }

  for (int kt = 0; kt <= qt; ++kt) {
    const int k0 = kt * 64;

    // K/V A-fragments straight from global (16 B/lane, coalesced)
    bhalf8 ak[4][2], av[4][2];
#pragma unroll
    for (int nt = 0; nt < 4; ++nt) {
      const BF16* kp = Kmat + bh_off + (size_t)(k0 + nt * 16 + lm) * 64 + quad * 8;
      ak[nt][0] = *(const bhalf8*)kp;
      ak[nt][1] = *(const bhalf8*)(kp + 32);
      const BF16* vp = VT + bh_off + (size_t)(nt * 16 + lm) * 2048 + k0 + quad * 8;
      av[nt][0] = *(const bhalf8*)vp;
      av[nt][1] = *(const bhalf8*)(vp + 32);
    }

#pragma unroll
    for (int s2 = 0; s2 < 4; ++s2) {
      const int qb = qb0 + s2 * 16;
      if (k0 > qb + 15) continue;  // fully masked (wave-uniform)

      // S^T = K·Q^T : C[row=kcol][col=qrow=lm]
      floatx4 st[4];
#pragma unroll
      for (int nt = 0; nt < 4; ++nt) {
        floatx4 z = (floatx4){0.f, 0.f, 0.f, 0.f};
        z = MFMA16(ak[nt][0], aq[s2][0], z);
        z = MFMA16(ak[nt][1], aq[s2][1], z);
        st[nt] = z;
      }

      if (k0 + 63 > qb) {  // boundary tile: per-element causal mask
#pragma unroll
        for (int nt = 0; nt < 4; ++nt)
#pragma unroll
          for (int r = 0; r < 4; ++r)
            if ((k0 + nt * 16 + quad * 4 + r) > (qb + lm)) st[nt][r] = MASKV;
      }

      // online softmax (log2 domain): 15 in-lane max + 2 shuffles
      float mx = MASKV;
#pragma unroll
      for (int nt = 0; nt < 4; ++nt)
#pragma unroll
        for (int r = 0; r < 4; ++r) mx = fmaxf(mx, st[nt][r]);
      mx = fmaxf(mx, __shfl_xor(mx, 16, 64));
      mx = fmaxf(mx, __shfl_xor(mx, 32, 64));
      const float mnew = fmaxf(m_i[s2], mx);
      const float alpha = __builtin_amdgcn_exp2f(m_i[s2] - mnew);
      m_i[s2] = mnew;

      float rs = 0.f;
#pragma unroll
      for (int nt = 0; nt < 4; ++nt)
#pragma unroll
        for (int r = 0; r < 4; ++r) {
          const float p = __builtin_amdgcn_exp2f(st[nt][r] - mnew);
          st[nt][r] = p;
          rs += p;
        }
      rs += __shfl_xor(rs, 16, 64);
      rs += __shfl_xor(rs, 32, 64);
      l_i[s2] = l_i[s2] * alpha + rs;
#pragma unroll
      for (int dn = 0; dn < 4; ++dn) oacc[s2][dn] *= alpha;

      // P^T -> this wave/set's LDS region: row=q (lm), 4 consecutive k -> 8 B
      BF16* pws = Ps[w][s2];
#pragma unroll
      for (int nt = 0; nt < 4; ++nt) {
        union { ushort4 u4; ushort u[4]; } pk;
#pragma unroll
        for (int r = 0; r < 4; ++r) {
          BF16 h = __float2bfloat16(st[nt][r]);
          pk.u[r] = *(const ushort*)&h;
        }
        const int g = ((nt * 2 + (quad >> 1)) + lm) & 7;
        *(ushort4*)(pws + lm * 64 + g * 8 + (quad & 1) * 4) = pk.u4;
      }

      // O^T += V^T·P^T (B-frag = P^T row lm; compiler inserts lgkm waits)
      const bhalf8 ap0 = *(const bhalf8*)(pws + lm * 64 + ((quad + lm) & 7) * 8);
      const bhalf8 ap1 = *(const bhalf8*)(pws + lm * 64 + ((4 + quad + lm) & 7) * 8);
#pragma unroll
      for (int dn = 0; dn < 4; ++dn) {
        oacc[s2][dn] = MFMA16(av[dn][0], ap0, oacc[s2][dn]);
        oacc[s2][dn] = MFMA16(av[dn][1], ap1, oacc[s2][dn]);
      }
    }
  }

  // normalize + store merged-heads (B*S, 1024); 4 consecutive d -> 8 B store
  const int b = bh >> 4, h = bh & 15;
#pragma unroll
  for (int s2 = 0; s2 < 4; ++s2) {
    const float inv_l = 1.0f / l_i[s2];
    const size_t orow = (size_t)(b * 2048 + qb0 + s2 * 16 + lm) * 1024 + h * 64;
#pragma unroll
    for (int dn = 0; dn < 4; ++dn) {
      union { ushort4 u4; ushort u[4]; } pk;
#pragma unroll
      for (int r = 0; r < 4; ++r) {
        BF16 h2 = __float2bfloat16(oacc[s2][dn][r] * inv_l);
        pk.u[r] = *(const ushort*)&h2;
      }
      *(ushort4*)(O + orow + dn * 16 + quad * 4) = pk.u4;
    }
  }
}

// ---------------------------------------------------------------------------
extern "C" void kernel_launch(void* const* d_in, const int* in_sizes, int n_in,
                              void* d_out, int out_size, void* d_ws, size_t ws_size,
                              hipStream_t stream) {
  const float* x = (const float*)d_in[0];      // (8192, 1024) f32
  const float* w_qkv = (const float*)d_in[1];  // (1024, 3072) f32
  const float* b_qkv = (const float*)d_in[2];  // (3072) f32
  const float* w_fc = (const float*)d_in[3];   // (1024, 1024) f32
  const float* b_fc = (const float*)d_in[4];   // (1024) f32
  float* out = (float*)d_out;                  // (8192, 1024) f32

  BF16* ws = (BF16*)d_ws;
  BF16* wTqkv = ws;                    // 3072*1024 bf16
  BF16* wTfc = wTqkv + 3072 * 1024;    // 1024*1024
  BF16* xb = wTfc + 1024 * 1024;       // 8192*1024 bf16
  BF16* Qb = xb + 8388608;             // (B,H,S,64)  pre-scaled by QSCALE
  BF16* Kb = Qb + 8388608;             // (B,H,S,64)
  BF16* VTb = Kb + 8388608;            // (B,H,64,S)
  BF16* Ob = VTb + 8388608;            // (B*S, 1024)
  // total ~92 MB of d_ws

  cvt_f32_bf16<<<4096, 256, 0, stream>>>(x, xb);
  transpose_cvt<<<dim3(96, 32), dim3(32, 8), 0, stream>>>(w_qkv, (ushort*)wTqkv, 1024, 3072);
  transpose_cvt<<<dim3(32, 32), dim3(32, 8), 0, stream>>>(w_fc, (ushort*)wTfc, 1024, 1024);

  gemm_bt<1><<<dim3(24, 64), 256, 0, stream>>>(
      xb, wTqkv, b_qkv, (void*)Qb, Kb, VTb, 8192, 3072, 1024);
  flash_attn<<<dim3(8, 64), 256, 0, stream>>>(Qb, Kb, VTb, Ob);
  gemm_bt<0><<<dim3(8, 64), 256, 0, stream>>>(
      Ob, wTfc, b_fc, (void*)out, nullptr, nullptr, 8192, 1024, 1024);
}